// Round 7
// baseline (4235.615 us; speedup 1.0000x reference)
//
#include <hip/hip_runtime.h>

typedef unsigned short u16;

__device__ __forceinline__ float bf2f(u16 u) {
    return __uint_as_float(((unsigned int)u) << 16);
}
__device__ __forceinline__ u16 f2bf(float f) {
    unsigned int x = __float_as_uint(f);
    return (u16)((x + 0x7fffu + ((x >> 16) & 1u)) >> 16);
}

// =============== on-device weight prep (algebraic collapse) ===============
__device__ __forceinline__ void mm64(const float* A, const float* B, float* C, int lane)
{
    float bcol[64];
#pragma unroll
    for (int m = 0; m < 64; ++m) bcol[m] = B[m*64 + lane];
    for (int k = 0; k < 64; ++k) {
        float acc = 0.f;
#pragma unroll
        for (int m = 0; m < 64; ++m) acc = fmaf(A[k*64 + m], bcol[m], acc);
        C[k*64 + lane] = acc;
    }
}

__device__ __forceinline__ void vm64(const float* a, const float* B, const float* add,
                                     float* c, int lane)
{
    float acc = (add != 0) ? add[lane] : 0.f;
#pragma unroll
    for (int m = 0; m < 64; ++m) acc = fmaf(a[m], B[m*64 + lane], acc);
    c[lane] = acc;
}

__global__ __launch_bounds__(256) void prep_kernel(
    const float* vc_fw, const float* vc_fb, const float* vc_ow0,
    const float* vc_ow1, const float* vc_ob1,
    const float* cv_rw, const float* cv_fw, const float* cv_fb,
    const float* cv_ow0, const float* cv_ow1, const float* cv_ob1,
    const float* pw0, const float* pb0, const float* vhw0, const float* vhb0,
    float* Fc, float* gc, float* Hc, float* hc, float* Fv, float* gv,
    float* Pw, float* pbp, float* Vw, float* vbp)
{
    const int wv = threadIdx.x >> 6;
    const int lane = threadIdx.x & 63;
    if (wv == 0) {
        mm64(vc_fw, vc_ow0, Fc, lane);
        vm64(vc_fb, vc_ow0, 0, gc, lane);
    } else if (wv == 1) {
        mm64(vc_ow1, cv_rw, Hc, lane);
        vm64(vc_ob1, cv_rw, 0, hc, lane);
    } else if (wv == 2) {
        mm64(cv_fw, cv_ow0, Fv, lane);
        vm64(cv_fb, cv_ow0, 0, gv, lane);
    } else {
        mm64(cv_ow1, pw0, Pw, lane);
        vm64(cv_ob1, pw0, pb0, pbp, lane);
        mm64(cv_ow1, vhw0, Vw, lane);
        vm64(cv_ob1, vhw0, vhb0, vbp, lane);
    }
}

// =============== embeddings (fused with downstream per-node linears) ===============
__global__ __launch_bounds__(256) void embc_kernel(
    const float* __restrict__ X,
    const float* __restrict__ W0, const float* __restrict__ B0,
    const float* __restrict__ W1, const float* __restrict__ B1,
    const float* __restrict__ LW, const float* __restrict__ LB,
    u16* __restrict__ c0out, float* __restrict__ RlOut, int M)
{
    const int lane = threadIdx.x & 63;
    const int wv   = threadIdx.x >> 6;
    __shared__ __align__(16) float xs[4][8*5];
    __shared__ __align__(16) float hb[4][8][64];
    __shared__ __align__(16) float yb[4][8][64];
    const int rowTile = (blockIdx.x*4 + wv)*8;

    for (int idx = lane; idx < 8*5; idx += 64) {
        long gi = (long)rowTile*5 + idx;
        xs[wv][idx] = (gi < (long)M*5) ? X[gi] : 0.f;
    }
    {
        float w0[5];
#pragma unroll
        for (int k = 0; k < 5; ++k) w0[k] = W0[k*64 + lane];
        const float b0 = B0[lane];
#pragma unroll
        for (int r = 0; r < 8; ++r) {
            float acc = b0;
#pragma unroll
            for (int k = 0; k < 5; ++k) acc = fmaf(xs[wv][r*5 + k], w0[k], acc);
            hb[wv][r][lane] = fmaxf(acc, 0.f);
        }
    }
    {
        float w1[64];
#pragma unroll
        for (int k = 0; k < 64; ++k) w1[k] = W1[k*64 + lane];
        const float b1 = B1[lane];
#pragma unroll
        for (int r = 0; r < 8; ++r) {
            float acc = b1;
#pragma unroll
            for (int k4 = 0; k4 < 16; ++k4) {
                float4 h4 = *(const float4*)&hb[wv][r][k4*4];
                acc = fmaf(h4.x, w1[k4*4+0], acc);
                acc = fmaf(h4.y, w1[k4*4+1], acc);
                acc = fmaf(h4.z, w1[k4*4+2], acc);
                acc = fmaf(h4.w, w1[k4*4+3], acc);
            }
            float y = fmaxf(acc, 0.f);
            yb[wv][r][lane] = y;
            int row = rowTile + r;
            if (row < M) c0out[(size_t)row*64 + lane] = f2bf(y);
        }
    }
    {
        float w[64];
#pragma unroll
        for (int k = 0; k < 64; ++k) w[k] = LW[k*64 + lane];
        const float bb = LB[lane];
#pragma unroll
        for (int r = 0; r < 8; ++r) {
            float acc = bb;
#pragma unroll
            for (int k4 = 0; k4 < 16; ++k4) {
                float4 y4 = *(const float4*)&yb[wv][r][k4*4];
                acc = fmaf(y4.x, w[k4*4+0], acc);
                acc = fmaf(y4.y, w[k4*4+1], acc);
                acc = fmaf(y4.z, w[k4*4+2], acc);
                acc = fmaf(y4.w, w[k4*4+3], acc);
            }
            int row = rowTile + r;
            if (row < M) RlOut[(size_t)row*64 + lane] = acc;
        }
    }
}

__global__ __launch_bounds__(256) void embv_kernel(
    const float* __restrict__ X,
    const float* __restrict__ W0, const float* __restrict__ B0,
    const float* __restrict__ W1, const float* __restrict__ B1,
    const float* __restrict__ RW,
    const float* __restrict__ LW, const float* __restrict__ LB,
    u16* __restrict__ v0out, u16* __restrict__ LsOut,
    float* __restrict__ RlOut, int M)
{
    const int lane = threadIdx.x & 63;
    const int wv   = threadIdx.x >> 6;
    __shared__ __align__(16) float xs[4][8*19];
    __shared__ __align__(16) float hb[4][8][64];
    __shared__ __align__(16) float yb[4][8][64];
    const int rowTile = (blockIdx.x*4 + wv)*8;

    for (int idx = lane; idx < 8*19; idx += 64) {
        long gi = (long)rowTile*19 + idx;
        xs[wv][idx] = (gi < (long)M*19) ? X[gi] : 0.f;
    }
    {
        float w0[19];
#pragma unroll
        for (int k = 0; k < 19; ++k) w0[k] = W0[k*64 + lane];
        const float b0 = B0[lane];
#pragma unroll
        for (int r = 0; r < 8; ++r) {
            float acc = b0;
#pragma unroll
            for (int k = 0; k < 19; ++k) acc = fmaf(xs[wv][r*19 + k], w0[k], acc);
            hb[wv][r][lane] = fmaxf(acc, 0.f);
        }
    }
    {
        float w1[64];
#pragma unroll
        for (int k = 0; k < 64; ++k) w1[k] = W1[k*64 + lane];
        const float b1 = B1[lane];
#pragma unroll
        for (int r = 0; r < 8; ++r) {
            float acc = b1;
#pragma unroll
            for (int k4 = 0; k4 < 16; ++k4) {
                float4 h4 = *(const float4*)&hb[wv][r][k4*4];
                acc = fmaf(h4.x, w1[k4*4+0], acc);
                acc = fmaf(h4.y, w1[k4*4+1], acc);
                acc = fmaf(h4.z, w1[k4*4+2], acc);
                acc = fmaf(h4.w, w1[k4*4+3], acc);
            }
            float y = fmaxf(acc, 0.f);
            yb[wv][r][lane] = y;
            int row = rowTile + r;
            if (row < M) v0out[(size_t)row*64 + lane] = f2bf(y);
        }
    }
    {
        float w[64];
#pragma unroll
        for (int k = 0; k < 64; ++k) w[k] = RW[k*64 + lane];
#pragma unroll
        for (int r = 0; r < 8; ++r) {
            float acc = 0.f;
#pragma unroll
            for (int k4 = 0; k4 < 16; ++k4) {
                float4 y4 = *(const float4*)&yb[wv][r][k4*4];
                acc = fmaf(y4.x, w[k4*4+0], acc);
                acc = fmaf(y4.y, w[k4*4+1], acc);
                acc = fmaf(y4.z, w[k4*4+2], acc);
                acc = fmaf(y4.w, w[k4*4+3], acc);
            }
            int row = rowTile + r;
            if (row < M) LsOut[(size_t)row*64 + lane] = f2bf(acc);
        }
    }
    {
        float w[64];
#pragma unroll
        for (int k = 0; k < 64; ++k) w[k] = LW[k*64 + lane];
        const float bb = LB[lane];
#pragma unroll
        for (int r = 0; r < 8; ++r) {
            float acc = bb;
#pragma unroll
            for (int k4 = 0; k4 < 16; ++k4) {
                float4 y4 = *(const float4*)&yb[wv][r][k4*4];
                acc = fmaf(y4.x, w[k4*4+0], acc);
                acc = fmaf(y4.y, w[k4*4+1], acc);
                acc = fmaf(y4.z, w[k4*4+2], acc);
                acc = fmaf(y4.w, w[k4*4+3], acc);
            }
            int row = rowTile + r;
            if (row < M) RlOut[(size_t)row*64 + lane] = acc;
        }
    }
}

// =============== counting sort ===============
__global__ __launch_bounds__(256) void hist2_kernel(
    const int* __restrict__ eic, const int* __restrict__ eiv,
    int* cntC, int* cntV, int E)
{
    int e = blockIdx.x*256 + threadIdx.x;
    if (e >= E) return;
    atomicAdd(&cntC[eic[e]], 1);
    atomicAdd(&cntV[eiv[e]], 1);
}

__global__ __launch_bounds__(256) void scan1_kernel(const int* __restrict__ in, int* blks, int N)
{
    __shared__ int sm[256];
    const int t = threadIdx.x;
    const int base = blockIdx.x*1024 + t*4;
    int s = 0;
#pragma unroll
    for (int i = 0; i < 4; ++i) { int idx = base + i; if (idx < N) s += in[idx]; }
    sm[t] = s; __syncthreads();
    for (int d = 128; d > 0; d >>= 1) { if (t < d) sm[t] += sm[t + d]; __syncthreads(); }
    if (t == 0) blks[blockIdx.x] = sm[0];
}

__global__ __launch_bounds__(256) void scan2_kernel(const int* __restrict__ blks, int* blkex, int nb)
{
    __shared__ int sm[1024];
    for (int i = threadIdx.x; i < nb; i += 256) sm[i] = blks[i];
    __syncthreads();
    if (threadIdx.x == 0) { int a = 0; for (int i = 0; i < nb; ++i) { int v = sm[i]; sm[i] = a; a += v; } }
    __syncthreads();
    for (int i = threadIdx.x; i < nb; i += 256) blkex[i] = sm[i];
}

__global__ __launch_bounds__(256) void scan3_kernel(
    const int* __restrict__ in, const int* __restrict__ blkex, int* out, int N)
{
    __shared__ int sm[256];
    const int t = threadIdx.x;
    const int base = blockIdx.x*1024 + t*4;
    int v[4]; int s = 0;
#pragma unroll
    for (int i = 0; i < 4; ++i) { int idx = base + i; v[i] = (idx < N) ? in[idx] : 0; s += v[i]; }
    sm[t] = s; __syncthreads();
    int x = s;
    for (int d = 1; d < 256; d <<= 1) {
        int y = (t >= d) ? sm[t - d] : 0;
        __syncthreads();
        x += y; sm[t] = x;
        __syncthreads();
    }
    int off0 = blkex[blockIdx.x] + (x - s);
#pragma unroll
    for (int i = 0; i < 4; ++i) {
        int idx = base + i;
        if (idx < N) {
            out[idx] = off0;
            off0 += v[i];
            if (idx == N - 1) out[N] = off0;
        }
    }
}

// scatter both directions in one pass over the edge stream
__global__ __launch_bounds__(256) void scatter2_kernel(
    const int* __restrict__ eic, const int* __restrict__ eiv,
    const float* __restrict__ ef,
    int* curC, int* curV, float2* __restrict__ bC, float2* __restrict__ bV, int E)
{
    int e = blockIdx.x*256 + threadIdx.x;
    if (e >= E) return;
    const int c = eic[e], v = eiv[e];
    const float f = ef[e];
    int pc = atomicAdd(&curC[c], 1);
    bC[pc] = make_float2(__int_as_float(v), f);
    int pv = atomicAdd(&curV[v], 1);
    bV[pv] = make_float2(__int_as_float(c), f);
}

// =============== bucketed aggregation, 8-deep gather pipeline ===============
__global__ __launch_bounds__(256) void agg_kernel(
    const int* __restrict__ off, const float2* __restrict__ bucket,
    float* RlA, const u16* __restrict__ Lsb,
    const float* __restrict__ ew, int N)
{
    const int node = blockIdx.x*4 + (threadIdx.x >> 6);
    if (node >= N) return;
    const int lane = threadIdx.x & 63;
    const int s0 = off[node];
    const int e1 = off[node + 1];
    const float rl = RlA[(size_t)node*64 + lane];
    const float w  = ew[lane];

    float acc = 0.f;
    int j = s0;
    for (; j + 8 <= e1; j += 8) {
        float2 q0 = bucket[j+0], q1 = bucket[j+1], q2 = bucket[j+2], q3 = bucket[j+3];
        float2 q4 = bucket[j+4], q5 = bucket[j+5], q6 = bucket[j+6], q7 = bucket[j+7];
        float l0 = bf2f(Lsb[(size_t)__float_as_int(q0.x)*64 + lane]);
        float l1 = bf2f(Lsb[(size_t)__float_as_int(q1.x)*64 + lane]);
        float l2 = bf2f(Lsb[(size_t)__float_as_int(q2.x)*64 + lane]);
        float l3 = bf2f(Lsb[(size_t)__float_as_int(q3.x)*64 + lane]);
        float l4 = bf2f(Lsb[(size_t)__float_as_int(q4.x)*64 + lane]);
        float l5 = bf2f(Lsb[(size_t)__float_as_int(q5.x)*64 + lane]);
        float l6 = bf2f(Lsb[(size_t)__float_as_int(q6.x)*64 + lane]);
        float l7 = bf2f(Lsb[(size_t)__float_as_int(q7.x)*64 + lane]);
        acc += fmaxf(fmaf(q0.y, w, rl + l0), 0.f);
        acc += fmaxf(fmaf(q1.y, w, rl + l1), 0.f);
        acc += fmaxf(fmaf(q2.y, w, rl + l2), 0.f);
        acc += fmaxf(fmaf(q3.y, w, rl + l3), 0.f);
        acc += fmaxf(fmaf(q4.y, w, rl + l4), 0.f);
        acc += fmaxf(fmaf(q5.y, w, rl + l5), 0.f);
        acc += fmaxf(fmaf(q6.y, w, rl + l6), 0.f);
        acc += fmaxf(fmaf(q7.y, w, rl + l7), 0.f);
    }
    for (; j < e1; ++j) {
        float2 q = bucket[j];
        float l = bf2f(Lsb[(size_t)__float_as_int(q.x)*64 + lane]);
        acc += fmaxf(fmaf(q.y, w, rl + l), 0.f);
    }
    RlA[(size_t)node*64 + lane] = acc;
}

// =============== fused cons update (8 rows/wave, sequential single-weight passes) ===============
// u = relu(agg@Fc + c0@OW0B + deg*gc + ob0);  Ls_c = u@Hc + hc  (bf16)
__global__ __launch_bounds__(256, 2) void consupd_kernel(
    const float* __restrict__ aggpre, const u16* __restrict__ c0,
    const int* __restrict__ off,
    const float* __restrict__ Fc, const float* __restrict__ OW0B,
    const float* __restrict__ gc, const float* __restrict__ ob0,
    const float* __restrict__ Hc, const float* __restrict__ hc,
    u16* __restrict__ LsOut, int M)
{
    const int lane = threadIdx.x & 63;
    const int wv   = threadIdx.x >> 6;
    __shared__ __align__(16) float xs[4][8][64];
    __shared__ __align__(16) float cs[4][8][64];
    const int rowTile = (blockIdx.x*4 + wv)*8;

    const float g_l = gc[lane], b_l = ob0[lane];
    float acc[8];
#pragma unroll
    for (int r = 0; r < 8; ++r) {
        int row = rowTile + r;
        int grow = (row < M) ? row : (M - 1);
        xs[wv][r][lane] = aggpre[(size_t)grow*64 + lane];
        cs[wv][r][lane] = bf2f(c0[(size_t)grow*64 + lane]);
        acc[r] = fmaf((float)(off[grow + 1] - off[grow]), g_l, b_l);
    }
    {   // pass A: agg @ Fc (only Fc column live)
        float w[64];
#pragma unroll
        for (int k = 0; k < 64; ++k) w[k] = Fc[k*64 + lane];
#pragma unroll
        for (int k4 = 0; k4 < 16; ++k4) {
#pragma unroll
            for (int r = 0; r < 8; ++r) {
                float4 x4 = *(const float4*)&xs[wv][r][k4*4];
                acc[r] = fmaf(x4.x, w[k4*4+0], acc[r]);
                acc[r] = fmaf(x4.y, w[k4*4+1], acc[r]);
                acc[r] = fmaf(x4.z, w[k4*4+2], acc[r]);
                acc[r] = fmaf(x4.w, w[k4*4+3], acc[r]);
            }
        }
    }
    __builtin_amdgcn_sched_barrier(0);
    {   // pass B: c0 @ OW0B
        float w[64];
#pragma unroll
        for (int k = 0; k < 64; ++k) w[k] = OW0B[k*64 + lane];
#pragma unroll
        for (int k4 = 0; k4 < 16; ++k4) {
#pragma unroll
            for (int r = 0; r < 8; ++r) {
                float4 c4 = *(const float4*)&cs[wv][r][k4*4];
                acc[r] = fmaf(c4.x, w[k4*4+0], acc[r]);
                acc[r] = fmaf(c4.y, w[k4*4+1], acc[r]);
                acc[r] = fmaf(c4.z, w[k4*4+2], acc[r]);
                acc[r] = fmaf(c4.w, w[k4*4+3], acc[r]);
            }
        }
    }
    __builtin_amdgcn_sched_barrier(0);
#pragma unroll
    for (int r = 0; r < 8; ++r) xs[wv][r][lane] = fmaxf(acc[r], 0.f);
    {   // pass C: u @ Hc + hc
        float w[64];
#pragma unroll
        for (int k = 0; k < 64; ++k) w[k] = Hc[k*64 + lane];
        const float h_l = hc[lane];
#pragma unroll
        for (int r = 0; r < 8; ++r) acc[r] = h_l;
#pragma unroll
        for (int k4 = 0; k4 < 16; ++k4) {
#pragma unroll
            for (int r = 0; r < 8; ++r) {
                float4 u4 = *(const float4*)&xs[wv][r][k4*4];
                acc[r] = fmaf(u4.x, w[k4*4+0], acc[r]);
                acc[r] = fmaf(u4.y, w[k4*4+1], acc[r]);
                acc[r] = fmaf(u4.z, w[k4*4+2], acc[r]);
                acc[r] = fmaf(u4.w, w[k4*4+3], acc[r]);
            }
        }
#pragma unroll
        for (int r = 0; r < 8; ++r) {
            int row = rowTile + r;
            if (row < M) LsOut[(size_t)row*64 + lane] = f2bf(acc[r]);
        }
    }
}

// =============== fused var update + heads (8 rows/wave, sequential passes) ===============
__global__ __launch_bounds__(256, 2) void varupdhead_kernel(
    const float* __restrict__ aggpre, const u16* __restrict__ v0,
    const int* __restrict__ off,
    const float* __restrict__ Fv, const float* __restrict__ OW0B,
    const float* __restrict__ gv, const float* __restrict__ ob0,
    const float* __restrict__ Pw, const float* __restrict__ pbp, const float* __restrict__ pw1,
    const float* __restrict__ Vw, const float* __restrict__ vbp, const float* __restrict__ vw1,
    const float* __restrict__ vb1,
    float* __restrict__ out, int M)
{
    const int lane = threadIdx.x & 63;
    const int wv   = threadIdx.x >> 6;
    __shared__ __align__(16) float xs[4][8][64];
    __shared__ __align__(16) float cs[4][8][64];
    const int rowTile = (blockIdx.x*4 + wv)*8;

    const float g_l = gv[lane], b_l = ob0[lane];
    float acc[8];
#pragma unroll
    for (int r = 0; r < 8; ++r) {
        int row = rowTile + r;
        int grow = (row < M) ? row : (M - 1);
        xs[wv][r][lane] = aggpre[(size_t)grow*64 + lane];
        cs[wv][r][lane] = bf2f(v0[(size_t)grow*64 + lane]);
        acc[r] = fmaf((float)(off[grow + 1] - off[grow]), g_l, b_l);
    }
    {   // pass A: agg @ Fv
        float w[64];
#pragma unroll
        for (int k = 0; k < 64; ++k) w[k] = Fv[k*64 + lane];
#pragma unroll
        for (int k4 = 0; k4 < 16; ++k4) {
#pragma unroll
            for (int r = 0; r < 8; ++r) {
                float4 x4 = *(const float4*)&xs[wv][r][k4*4];
                acc[r] = fmaf(x4.x, w[k4*4+0], acc[r]);
                acc[r] = fmaf(x4.y, w[k4*4+1], acc[r]);
                acc[r] = fmaf(x4.z, w[k4*4+2], acc[r]);
                acc[r] = fmaf(x4.w, w[k4*4+3], acc[r]);
            }
        }
    }
    __builtin_amdgcn_sched_barrier(0);
    {   // pass B: v0 @ OW0B
        float w[64];
#pragma unroll
        for (int k = 0; k < 64; ++k) w[k] = OW0B[k*64 + lane];
#pragma unroll
        for (int k4 = 0; k4 < 16; ++k4) {
#pragma unroll
            for (int r = 0; r < 8; ++r) {
                float4 c4 = *(const float4*)&cs[wv][r][k4*4];
                acc[r] = fmaf(c4.x, w[k4*4+0], acc[r]);
                acc[r] = fmaf(c4.y, w[k4*4+1], acc[r]);
                acc[r] = fmaf(c4.z, w[k4*4+2], acc[r]);
                acc[r] = fmaf(c4.w, w[k4*4+3], acc[r]);
            }
        }
    }
    __builtin_amdgcn_sched_barrier(0);
#pragma unroll
    for (int r = 0; r < 8; ++r) xs[wv][r][lane] = fmaxf(acc[r], 0.f);

    float tp[8];
    {   // policy head pass: u @ Pw
        float w[64];
#pragma unroll
        for (int k = 0; k < 64; ++k) w[k] = Pw[k*64 + lane];
        const float pb_l = pbp[lane];
#pragma unroll
        for (int r = 0; r < 8; ++r) tp[r] = pb_l;
#pragma unroll
        for (int k4 = 0; k4 < 16; ++k4) {
#pragma unroll
            for (int r = 0; r < 8; ++r) {
                float4 u4 = *(const float4*)&xs[wv][r][k4*4];
                tp[r] = fmaf(u4.x, w[k4*4+0], tp[r]);
                tp[r] = fmaf(u4.y, w[k4*4+1], tp[r]);
                tp[r] = fmaf(u4.z, w[k4*4+2], tp[r]);
                tp[r] = fmaf(u4.w, w[k4*4+3], tp[r]);
            }
        }
    }
    __builtin_amdgcn_sched_barrier(0);
    {   // value head pass: u @ Vw (reuses acc[])
        float w[64];
#pragma unroll
        for (int k = 0; k < 64; ++k) w[k] = Vw[k*64 + lane];
        const float vb_l = vbp[lane];
#pragma unroll
        for (int r = 0; r < 8; ++r) acc[r] = vb_l;
#pragma unroll
        for (int k4 = 0; k4 < 16; ++k4) {
#pragma unroll
            for (int r = 0; r < 8; ++r) {
                float4 u4 = *(const float4*)&xs[wv][r][k4*4];
                acc[r] = fmaf(u4.x, w[k4*4+0], acc[r]);
                acc[r] = fmaf(u4.y, w[k4*4+1], acc[r]);
                acc[r] = fmaf(u4.z, w[k4*4+2], acc[r]);
                acc[r] = fmaf(u4.w, w[k4*4+3], acc[r]);
            }
        }
    }
    const float p1w = pw1[lane], v1w = vw1[lane];
    const float vbias = vb1[0];
#pragma unroll
    for (int r = 0; r < 8; ++r) {
        float a = fmaxf(tp[r],  0.f) * p1w;
        float b = fmaxf(acc[r], 0.f) * v1w;
#pragma unroll
        for (int m = 32; m >= 1; m >>= 1) {
            a += __shfl_xor(a, m, 64);
            b += __shfl_xor(b, m, 64);
        }
        int row = rowTile + r;
        if (lane == 0 && row < M) {
            out[row]     = b + vbias;   // value
            out[M + row] = a;           // policy
        }
    }
}

// =============== host launch ===============
#define AL256(x) (((x) + 255) & ~(size_t)255)

extern "C" void kernel_launch(void* const* d_in, const int* in_sizes, int n_in,
                              void* d_out, int out_size, void* d_ws, size_t ws_size,
                              hipStream_t stream)
{
    const float* cf  = (const float*)d_in[0];
    const int*   ei  = (const int*)  d_in[1];
    const float* ef  = (const float*)d_in[2];
    const float* vf  = (const float*)d_in[3];

    const float* cw0 = (const float*)d_in[4];
    const float* cb0 = (const float*)d_in[5];
    const float* cw1 = (const float*)d_in[6];
    const float* cb1 = (const float*)d_in[7];
    const float* vw0 = (const float*)d_in[8];
    const float* vb0 = (const float*)d_in[9];
    const float* vw1 = (const float*)d_in[10];
    const float* vb1 = (const float*)d_in[11];

    const float* vc_lw  = (const float*)d_in[12];
    const float* vc_lb  = (const float*)d_in[13];
    const float* vc_ew  = (const float*)d_in[14];
    const float* vc_rw  = (const float*)d_in[15];
    const float* vc_fw  = (const float*)d_in[16];
    const float* vc_fb  = (const float*)d_in[17];
    const float* vc_ow0 = (const float*)d_in[18];
    const float* vc_ob0 = (const float*)d_in[19];
    const float* vc_ow1 = (const float*)d_in[20];
    const float* vc_ob1 = (const float*)d_in[21];

    const float* cv_lw  = (const float*)d_in[22];
    const float* cv_lb  = (const float*)d_in[23];
    const float* cv_ew  = (const float*)d_in[24];
    const float* cv_rw  = (const float*)d_in[25];
    const float* cv_fw  = (const float*)d_in[26];
    const float* cv_fb  = (const float*)d_in[27];
    const float* cv_ow0 = (const float*)d_in[28];
    const float* cv_ob0 = (const float*)d_in[29];
    const float* cv_ow1 = (const float*)d_in[30];
    const float* cv_ob1 = (const float*)d_in[31];

    const float* pw0  = (const float*)d_in[32];
    const float* pb0  = (const float*)d_in[33];
    const float* pw1  = (const float*)d_in[34];
    const float* vhw0 = (const float*)d_in[35];
    const float* vhb0 = (const float*)d_in[36];
    const float* vhw1 = (const float*)d_in[37];
    const float* vhb1 = (const float*)d_in[38];

    const int NC = in_sizes[0] / 5;
    const int E  = in_sizes[1] / 2;
    const int NV = in_sizes[3] / 19;
    const int* eic = ei;
    const int* eiv = ei + E;

    // ---- workspace layout ----
    char* base = (char*)d_ws;
    size_t o = 0;
    float*  RlC = (float*)(base + o);  o += AL256((size_t)NC*64*4);
    u16*    c0b = (u16*)  (base + o);  o += AL256((size_t)NC*64*2);
    u16*    LsC = (u16*)  (base + o);  o += AL256((size_t)NC*64*2);
    float*  RlV = (float*)(base + o);  o += AL256((size_t)NV*64*4);
    u16*    v0b = (u16*)  (base + o);  o += AL256((size_t)NV*64*2);
    u16*    LsV = (u16*)  (base + o);  o += AL256((size_t)NV*64*2);
    float2* bktC = (float2*)(base + o); o += AL256((size_t)E*8);
    float2* bktV = (float2*)(base + o); o += AL256((size_t)E*8);
    int* cntC = (int*)(base + o);  o += AL256((size_t)NC*4);
    int* offC = (int*)(base + o);  o += AL256(((size_t)NC + 1)*4);
    int* cntV = (int*)(base + o);  o += AL256((size_t)NV*4);
    int* offV = (int*)(base + o);  o += AL256(((size_t)NV + 1)*4);
    int* blks = (int*)(base + o);  o += AL256((size_t)1024*4);
    int* blkex= (int*)(base + o);  o += AL256((size_t)1024*4);
    float* Fc  = (float*)(base + o); o += AL256((size_t)4096*4);
    float* Hc  = (float*)(base + o); o += AL256((size_t)4096*4);
    float* Fv  = (float*)(base + o); o += AL256((size_t)4096*4);
    float* Pw  = (float*)(base + o); o += AL256((size_t)4096*4);
    float* Vw  = (float*)(base + o); o += AL256((size_t)4096*4);
    float* gc  = (float*)(base + o); o += AL256((size_t)64*4);
    float* hc  = (float*)(base + o); o += AL256((size_t)64*4);
    float* gv  = (float*)(base + o); o += AL256((size_t)64*4);
    float* pbp = (float*)(base + o); o += AL256((size_t)64*4);
    float* vbp = (float*)(base + o); o += AL256((size_t)64*4);

    if (o > ws_size) return;  // insufficient scratch: fail visibly

    dim3 blk(256);
    dim3 gRowsC((unsigned)((NC + 31) / 32));
    dim3 gRowsV((unsigned)((NV + 31) / 32));
    dim3 gNodeC((unsigned)((NC + 3) / 4));
    dim3 gNodeV((unsigned)((NV + 3) / 4));
    dim3 gE((unsigned)((E + 255) / 256));
    const int nbC = (NC + 1023) / 1024;
    const int nbV = (NV + 1023) / 1024;

    // ---- counting sort setup ----
    (void)hipMemsetAsync(cntC, 0, (size_t)NC*4, stream);
    (void)hipMemsetAsync(cntV, 0, (size_t)NV*4, stream);
    hist2_kernel<<<gE, blk, 0, stream>>>(eic, eiv, cntC, cntV, E);
    scan1_kernel<<<dim3(nbC), blk, 0, stream>>>(cntC, blks, NC);
    scan2_kernel<<<dim3(1),   blk, 0, stream>>>(blks, blkex, nbC);
    scan3_kernel<<<dim3(nbC), blk, 0, stream>>>(cntC, blkex, offC, NC);
    scan1_kernel<<<dim3(nbV), blk, 0, stream>>>(cntV, blks, NV);
    scan2_kernel<<<dim3(1),   blk, 0, stream>>>(blks, blkex, nbV);
    scan3_kernel<<<dim3(nbV), blk, 0, stream>>>(cntV, blkex, offV, NV);

    // ---- collapsed weights ----
    prep_kernel<<<dim3(1), blk, 0, stream>>>(
        vc_fw, vc_fb, vc_ow0, vc_ow1, vc_ob1,
        cv_rw, cv_fw, cv_fb, cv_ow0, cv_ow1, cv_ob1,
        pw0, pb0, vhw0, vhb0,
        Fc, gc, Hc, hc, Fv, gv, Pw, pbp, Vw, vbp);

    // ---- embeddings (+ fused per-node linears) ----
    embc_kernel<<<gRowsC, blk, 0, stream>>>(cf, cw0, cb0, cw1, cb1,
                                            vc_lw, vc_lb, c0b, RlC, NC);
    embv_kernel<<<gRowsV, blk, 0, stream>>>(vf, vw0, vb0, vw1, vb1,
                                            vc_rw, cv_lw, cv_lb, v0b, LsV, RlV, NV);

    // ---- single-pass scatter into both dst-sorted buckets ----
    (void)hipMemcpyAsync(cntC, offC, (size_t)NC*4, hipMemcpyDeviceToDevice, stream);
    (void)hipMemcpyAsync(cntV, offV, (size_t)NV*4, hipMemcpyDeviceToDevice, stream);
    scatter2_kernel<<<gE, blk, 0, stream>>>(eic, eiv, ef, cntC, cntV, bktC, bktV, E);

    // ---- conv1: v -> c ----
    agg_kernel<<<gNodeC, blk, 0, stream>>>(offC, bktC, RlC, LsV, vc_ew, NC);
    consupd_kernel<<<gRowsC, blk, 0, stream>>>(RlC, c0b, offC,
                                               Fc, vc_ow0 + 64*64, gc, vc_ob0,
                                               Hc, hc, LsC, NC);

    // ---- conv2: c -> v ----
    agg_kernel<<<gNodeV, blk, 0, stream>>>(offV, bktV, RlV, LsC, cv_ew, NV);
    varupdhead_kernel<<<gRowsV, blk, 0, stream>>>(RlV, v0b, offV,
                                                  Fv, cv_ow0 + 64*64, gv, cv_ob0,
                                                  Pw, pbp, pw1, Vw, vbp, vhw1, vhb1,
                                                  (float*)d_out, NV);
}

// Round 8
// 1215.991 us; speedup vs baseline: 3.4833x; 3.4833x over previous
//
#include <hip/hip_runtime.h>

typedef unsigned short u16;

__device__ __forceinline__ float bf2f(u16 u) {
    return __uint_as_float(((unsigned int)u) << 16);
}
__device__ __forceinline__ u16 f2bf(float f) {
    unsigned int x = __float_as_uint(f);
    return (u16)((x + 0x7fffu + ((x >> 16) & 1u)) >> 16);
}

// =============== on-device weight prep (algebraic collapse) ===============
__device__ __forceinline__ void mm64(const float* A, const float* B, float* C, int lane)
{
    float bcol[64];
#pragma unroll
    for (int m = 0; m < 64; ++m) bcol[m] = B[m*64 + lane];
    for (int k = 0; k < 64; ++k) {
        float acc = 0.f;
#pragma unroll
        for (int m = 0; m < 64; ++m) acc = fmaf(A[k*64 + m], bcol[m], acc);
        C[k*64 + lane] = acc;
    }
}

__device__ __forceinline__ void vm64(const float* a, const float* B, const float* add,
                                     float* c, int lane)
{
    float acc = (add != 0) ? add[lane] : 0.f;
#pragma unroll
    for (int m = 0; m < 64; ++m) acc = fmaf(a[m], B[m*64 + lane], acc);
    c[lane] = acc;
}

__global__ __launch_bounds__(256) void prep_kernel(
    const float* vc_fw, const float* vc_fb, const float* vc_ow0,
    const float* vc_ow1, const float* vc_ob1,
    const float* cv_rw, const float* cv_fw, const float* cv_fb,
    const float* cv_ow0, const float* cv_ow1, const float* cv_ob1,
    const float* pw0, const float* pb0, const float* vhw0, const float* vhb0,
    float* Fc, float* gc, float* Hc, float* hc, float* Fv, float* gv,
    float* Pw, float* pbp, float* Vw, float* vbp)
{
    const int wv = threadIdx.x >> 6;
    const int lane = threadIdx.x & 63;
    if (wv == 0) {
        mm64(vc_fw, vc_ow0, Fc, lane);
        vm64(vc_fb, vc_ow0, 0, gc, lane);
    } else if (wv == 1) {
        mm64(vc_ow1, cv_rw, Hc, lane);
        vm64(vc_ob1, cv_rw, 0, hc, lane);
    } else if (wv == 2) {
        mm64(cv_fw, cv_ow0, Fv, lane);
        vm64(cv_fb, cv_ow0, 0, gv, lane);
    } else {
        mm64(cv_ow1, pw0, Pw, lane);
        vm64(cv_ob1, pw0, pb0, pbp, lane);
        mm64(cv_ow1, vhw0, Vw, lane);
        vm64(cv_ob1, vhw0, vhb0, vbp, lane);
    }
}

// =============== embeddings (fused with downstream per-node linears) ===============
__global__ __launch_bounds__(256) void embc_kernel(
    const float* __restrict__ X,
    const float* __restrict__ W0, const float* __restrict__ B0,
    const float* __restrict__ W1, const float* __restrict__ B1,
    const float* __restrict__ LW, const float* __restrict__ LB,
    u16* __restrict__ c0out, float* __restrict__ RlOut, int M)
{
    const int lane = threadIdx.x & 63;
    const int wv   = threadIdx.x >> 6;
    __shared__ __align__(16) float xs[4][8*5];
    __shared__ __align__(16) float hb[4][8][64];
    __shared__ __align__(16) float yb[4][8][64];
    const int rowTile = (blockIdx.x*4 + wv)*8;

    for (int idx = lane; idx < 8*5; idx += 64) {
        long gi = (long)rowTile*5 + idx;
        xs[wv][idx] = (gi < (long)M*5) ? X[gi] : 0.f;
    }
    {
        float w0[5];
#pragma unroll
        for (int k = 0; k < 5; ++k) w0[k] = W0[k*64 + lane];
        const float b0 = B0[lane];
#pragma unroll
        for (int r = 0; r < 8; ++r) {
            float acc = b0;
#pragma unroll
            for (int k = 0; k < 5; ++k) acc = fmaf(xs[wv][r*5 + k], w0[k], acc);
            hb[wv][r][lane] = fmaxf(acc, 0.f);
        }
    }
    {
        float w1[64];
#pragma unroll
        for (int k = 0; k < 64; ++k) w1[k] = W1[k*64 + lane];
        const float b1 = B1[lane];
#pragma unroll
        for (int r = 0; r < 8; ++r) {
            float acc = b1;
#pragma unroll
            for (int k4 = 0; k4 < 16; ++k4) {
                float4 h4 = *(const float4*)&hb[wv][r][k4*4];
                acc = fmaf(h4.x, w1[k4*4+0], acc);
                acc = fmaf(h4.y, w1[k4*4+1], acc);
                acc = fmaf(h4.z, w1[k4*4+2], acc);
                acc = fmaf(h4.w, w1[k4*4+3], acc);
            }
            float y = fmaxf(acc, 0.f);
            yb[wv][r][lane] = y;
            int row = rowTile + r;
            if (row < M) c0out[(size_t)row*64 + lane] = f2bf(y);
        }
    }
    {
        float w[64];
#pragma unroll
        for (int k = 0; k < 64; ++k) w[k] = LW[k*64 + lane];
        const float bb = LB[lane];
#pragma unroll
        for (int r = 0; r < 8; ++r) {
            float acc = bb;
#pragma unroll
            for (int k4 = 0; k4 < 16; ++k4) {
                float4 y4 = *(const float4*)&yb[wv][r][k4*4];
                acc = fmaf(y4.x, w[k4*4+0], acc);
                acc = fmaf(y4.y, w[k4*4+1], acc);
                acc = fmaf(y4.z, w[k4*4+2], acc);
                acc = fmaf(y4.w, w[k4*4+3], acc);
            }
            int row = rowTile + r;
            if (row < M) RlOut[(size_t)row*64 + lane] = acc;
        }
    }
}

__global__ __launch_bounds__(256) void embv_kernel(
    const float* __restrict__ X,
    const float* __restrict__ W0, const float* __restrict__ B0,
    const float* __restrict__ W1, const float* __restrict__ B1,
    const float* __restrict__ RW,
    const float* __restrict__ LW, const float* __restrict__ LB,
    u16* __restrict__ v0out, u16* __restrict__ LsOut,
    float* __restrict__ RlOut, int M)
{
    const int lane = threadIdx.x & 63;
    const int wv   = threadIdx.x >> 6;
    __shared__ __align__(16) float xs[4][8*19];
    __shared__ __align__(16) float hb[4][8][64];
    __shared__ __align__(16) float yb[4][8][64];
    const int rowTile = (blockIdx.x*4 + wv)*8;

    for (int idx = lane; idx < 8*19; idx += 64) {
        long gi = (long)rowTile*19 + idx;
        xs[wv][idx] = (gi < (long)M*19) ? X[gi] : 0.f;
    }
    {
        float w0[19];
#pragma unroll
        for (int k = 0; k < 19; ++k) w0[k] = W0[k*64 + lane];
        const float b0 = B0[lane];
#pragma unroll
        for (int r = 0; r < 8; ++r) {
            float acc = b0;
#pragma unroll
            for (int k = 0; k < 19; ++k) acc = fmaf(xs[wv][r*19 + k], w0[k], acc);
            hb[wv][r][lane] = fmaxf(acc, 0.f);
        }
    }
    {
        float w1[64];
#pragma unroll
        for (int k = 0; k < 64; ++k) w1[k] = W1[k*64 + lane];
        const float b1 = B1[lane];
#pragma unroll
        for (int r = 0; r < 8; ++r) {
            float acc = b1;
#pragma unroll
            for (int k4 = 0; k4 < 16; ++k4) {
                float4 h4 = *(const float4*)&hb[wv][r][k4*4];
                acc = fmaf(h4.x, w1[k4*4+0], acc);
                acc = fmaf(h4.y, w1[k4*4+1], acc);
                acc = fmaf(h4.z, w1[k4*4+2], acc);
                acc = fmaf(h4.w, w1[k4*4+3], acc);
            }
            float y = fmaxf(acc, 0.f);
            yb[wv][r][lane] = y;
            int row = rowTile + r;
            if (row < M) v0out[(size_t)row*64 + lane] = f2bf(y);
        }
    }
    {
        float w[64];
#pragma unroll
        for (int k = 0; k < 64; ++k) w[k] = RW[k*64 + lane];
#pragma unroll
        for (int r = 0; r < 8; ++r) {
            float acc = 0.f;
#pragma unroll
            for (int k4 = 0; k4 < 16; ++k4) {
                float4 y4 = *(const float4*)&yb[wv][r][k4*4];
                acc = fmaf(y4.x, w[k4*4+0], acc);
                acc = fmaf(y4.y, w[k4*4+1], acc);
                acc = fmaf(y4.z, w[k4*4+2], acc);
                acc = fmaf(y4.w, w[k4*4+3], acc);
            }
            int row = rowTile + r;
            if (row < M) LsOut[(size_t)row*64 + lane] = f2bf(acc);
        }
    }
    {
        float w[64];
#pragma unroll
        for (int k = 0; k < 64; ++k) w[k] = LW[k*64 + lane];
        const float bb = LB[lane];
#pragma unroll
        for (int r = 0; r < 8; ++r) {
            float acc = bb;
#pragma unroll
            for (int k4 = 0; k4 < 16; ++k4) {
                float4 y4 = *(const float4*)&yb[wv][r][k4*4];
                acc = fmaf(y4.x, w[k4*4+0], acc);
                acc = fmaf(y4.y, w[k4*4+1], acc);
                acc = fmaf(y4.z, w[k4*4+2], acc);
                acc = fmaf(y4.w, w[k4*4+3], acc);
            }
            int row = rowTile + r;
            if (row < M) RlOut[(size_t)row*64 + lane] = acc;
        }
    }
}

// =============== counting sort ===============
__global__ __launch_bounds__(256) void hist2_kernel(
    const int* __restrict__ eic, const int* __restrict__ eiv,
    int* cntC, int* cntV, int E)
{
    int e = blockIdx.x*256 + threadIdx.x;
    if (e >= E) return;
    atomicAdd(&cntC[eic[e]], 1);
    atomicAdd(&cntV[eiv[e]], 1);
}

__global__ __launch_bounds__(256) void scan1_kernel(const int* __restrict__ in, int* blks, int N)
{
    __shared__ int sm[256];
    const int t = threadIdx.x;
    const int base = blockIdx.x*1024 + t*4;
    int s = 0;
#pragma unroll
    for (int i = 0; i < 4; ++i) { int idx = base + i; if (idx < N) s += in[idx]; }
    sm[t] = s; __syncthreads();
    for (int d = 128; d > 0; d >>= 1) { if (t < d) sm[t] += sm[t + d]; __syncthreads(); }
    if (t == 0) blks[blockIdx.x] = sm[0];
}

__global__ __launch_bounds__(256) void scan2_kernel(const int* __restrict__ blks, int* blkex, int nb)
{
    __shared__ int sm[1024];
    for (int i = threadIdx.x; i < nb; i += 256) sm[i] = blks[i];
    __syncthreads();
    if (threadIdx.x == 0) { int a = 0; for (int i = 0; i < nb; ++i) { int v = sm[i]; sm[i] = a; a += v; } }
    __syncthreads();
    for (int i = threadIdx.x; i < nb; i += 256) blkex[i] = sm[i];
}

__global__ __launch_bounds__(256) void scan3_kernel(
    const int* __restrict__ in, const int* __restrict__ blkex, int* out, int N)
{
    __shared__ int sm[256];
    const int t = threadIdx.x;
    const int base = blockIdx.x*1024 + t*4;
    int v[4]; int s = 0;
#pragma unroll
    for (int i = 0; i < 4; ++i) { int idx = base + i; v[i] = (idx < N) ? in[idx] : 0; s += v[i]; }
    sm[t] = s; __syncthreads();
    int x = s;
    for (int d = 1; d < 256; d <<= 1) {
        int y = (t >= d) ? sm[t - d] : 0;
        __syncthreads();
        x += y; sm[t] = x;
        __syncthreads();
    }
    int off0 = blkex[blockIdx.x] + (x - s);
#pragma unroll
    for (int i = 0; i < 4; ++i) {
        int idx = base + i;
        if (idx < N) {
            out[idx] = off0;
            off0 += v[i];
            if (idx == N - 1) out[N] = off0;
        }
    }
}

// scatter both directions in one pass over the edge stream
__global__ __launch_bounds__(256) void scatter2_kernel(
    const int* __restrict__ eic, const int* __restrict__ eiv,
    const float* __restrict__ ef,
    int* curC, int* curV, float2* __restrict__ bC, float2* __restrict__ bV, int E)
{
    int e = blockIdx.x*256 + threadIdx.x;
    if (e >= E) return;
    const int c = eic[e], v = eiv[e];
    const float f = ef[e];
    int pc = atomicAdd(&curC[c], 1);
    bC[pc] = make_float2(__int_as_float(v), f);
    int pv = atomicAdd(&curV[v], 1);
    bV[pv] = make_float2(__int_as_float(c), f);
}

// =============== bucketed aggregation, 8-deep gather pipeline ===============
__global__ __launch_bounds__(256) void agg_kernel(
    const int* __restrict__ off, const float2* __restrict__ bucket,
    float* RlA, const u16* __restrict__ Lsb,
    const float* __restrict__ ew, int N)
{
    const int node = blockIdx.x*4 + (threadIdx.x >> 6);
    if (node >= N) return;
    const int lane = threadIdx.x & 63;
    const int s0 = off[node];
    const int e1 = off[node + 1];
    const float rl = RlA[(size_t)node*64 + lane];
    const float w  = ew[lane];

    float acc = 0.f;
    int j = s0;
    for (; j + 8 <= e1; j += 8) {
        float2 q0 = bucket[j+0], q1 = bucket[j+1], q2 = bucket[j+2], q3 = bucket[j+3];
        float2 q4 = bucket[j+4], q5 = bucket[j+5], q6 = bucket[j+6], q7 = bucket[j+7];
        float l0 = bf2f(Lsb[(size_t)__float_as_int(q0.x)*64 + lane]);
        float l1 = bf2f(Lsb[(size_t)__float_as_int(q1.x)*64 + lane]);
        float l2 = bf2f(Lsb[(size_t)__float_as_int(q2.x)*64 + lane]);
        float l3 = bf2f(Lsb[(size_t)__float_as_int(q3.x)*64 + lane]);
        float l4 = bf2f(Lsb[(size_t)__float_as_int(q4.x)*64 + lane]);
        float l5 = bf2f(Lsb[(size_t)__float_as_int(q5.x)*64 + lane]);
        float l6 = bf2f(Lsb[(size_t)__float_as_int(q6.x)*64 + lane]);
        float l7 = bf2f(Lsb[(size_t)__float_as_int(q7.x)*64 + lane]);
        acc += fmaxf(fmaf(q0.y, w, rl + l0), 0.f);
        acc += fmaxf(fmaf(q1.y, w, rl + l1), 0.f);
        acc += fmaxf(fmaf(q2.y, w, rl + l2), 0.f);
        acc += fmaxf(fmaf(q3.y, w, rl + l3), 0.f);
        acc += fmaxf(fmaf(q4.y, w, rl + l4), 0.f);
        acc += fmaxf(fmaf(q5.y, w, rl + l5), 0.f);
        acc += fmaxf(fmaf(q6.y, w, rl + l6), 0.f);
        acc += fmaxf(fmaf(q7.y, w, rl + l7), 0.f);
    }
    for (; j < e1; ++j) {
        float2 q = bucket[j];
        float l = bf2f(Lsb[(size_t)__float_as_int(q.x)*64 + lane]);
        acc += fmaxf(fmaf(q.y, w, rl + l), 0.f);
    }
    RlA[(size_t)node*64 + lane] = acc;
}

// =============== fused cons update (round-5 structure, 256-VGPR budget) ===============
// u = relu(agg@Fc + c0@OW0B + deg*gc + ob0);  Ls_c = u@Hc + hc  (bf16)
__global__ __launch_bounds__(256, 1) void consupd_kernel(
    const float* __restrict__ aggpre, const u16* __restrict__ c0,
    const int* __restrict__ off,
    const float* __restrict__ Fc, const float* __restrict__ OW0B,
    const float* __restrict__ gc, const float* __restrict__ ob0,
    const float* __restrict__ Hc, const float* __restrict__ hc,
    u16* __restrict__ LsOut, int M)
{
    const int lane = threadIdx.x & 63;
    const int wv   = threadIdx.x >> 6;
    __shared__ __align__(16) float xs[4][8][64];
    __shared__ __align__(16) float cs[4][8][64];
    const int rowTile = (blockIdx.x*4 + wv)*8;

    float degv[8];
#pragma unroll
    for (int r = 0; r < 8; ++r) {
        int row = rowTile + r;
        int grow = (row < M) ? row : (M - 1);
        xs[wv][r][lane] = aggpre[(size_t)grow*64 + lane];
        cs[wv][r][lane] = bf2f(c0[(size_t)grow*64 + lane]);
        degv[r] = (float)(off[grow + 1] - off[grow]);
    }
    {   // stage 1 -> u in xs (both weight columns in registers)
        float wa[64], wb[64];
#pragma unroll
        for (int k = 0; k < 64; ++k) { wa[k] = Fc[k*64 + lane]; wb[k] = OW0B[k*64 + lane]; }
        const float g_l = gc[lane], b_l = ob0[lane];
#pragma unroll
        for (int r = 0; r < 8; ++r) {
            float acc = fmaf(degv[r], g_l, b_l);
#pragma unroll
            for (int k4 = 0; k4 < 16; ++k4) {
                float4 x4 = *(const float4*)&xs[wv][r][k4*4];
                float4 c4 = *(const float4*)&cs[wv][r][k4*4];
                acc = fmaf(x4.x, wa[k4*4+0], acc); acc = fmaf(c4.x, wb[k4*4+0], acc);
                acc = fmaf(x4.y, wa[k4*4+1], acc); acc = fmaf(c4.y, wb[k4*4+1], acc);
                acc = fmaf(x4.z, wa[k4*4+2], acc); acc = fmaf(c4.z, wb[k4*4+2], acc);
                acc = fmaf(x4.w, wa[k4*4+3], acc); acc = fmaf(c4.w, wb[k4*4+3], acc);
            }
            xs[wv][r][lane] = fmaxf(acc, 0.f);
        }
    }
    {   // stage 2 -> Ls_c bf16
        float wh[64];
#pragma unroll
        for (int k = 0; k < 64; ++k) wh[k] = Hc[k*64 + lane];
        const float h_l = hc[lane];
#pragma unroll
        for (int r = 0; r < 8; ++r) {
            float acc = h_l;
#pragma unroll
            for (int k4 = 0; k4 < 16; ++k4) {
                float4 u4 = *(const float4*)&xs[wv][r][k4*4];
                acc = fmaf(u4.x, wh[k4*4+0], acc);
                acc = fmaf(u4.y, wh[k4*4+1], acc);
                acc = fmaf(u4.z, wh[k4*4+2], acc);
                acc = fmaf(u4.w, wh[k4*4+3], acc);
            }
            int row = rowTile + r;
            if (row < M) LsOut[(size_t)row*64 + lane] = f2bf(acc);
        }
    }
}

// =============== fused var update + heads (round-5 structure, 256-VGPR budget) ===============
__global__ __launch_bounds__(256, 1) void varupdhead_kernel(
    const float* __restrict__ aggpre, const u16* __restrict__ v0,
    const int* __restrict__ off,
    const float* __restrict__ Fv, const float* __restrict__ OW0B,
    const float* __restrict__ gv, const float* __restrict__ ob0,
    const float* __restrict__ Pw, const float* __restrict__ pbp, const float* __restrict__ pw1,
    const float* __restrict__ Vw, const float* __restrict__ vbp, const float* __restrict__ vw1,
    const float* __restrict__ vb1,
    float* __restrict__ out, int M)
{
    const int lane = threadIdx.x & 63;
    const int wv   = threadIdx.x >> 6;
    __shared__ __align__(16) float xs[4][8][64];
    __shared__ __align__(16) float cs[4][8][64];
    const int rowTile = (blockIdx.x*4 + wv)*8;

    float degv[8];
#pragma unroll
    for (int r = 0; r < 8; ++r) {
        int row = rowTile + r;
        int grow = (row < M) ? row : (M - 1);
        xs[wv][r][lane] = aggpre[(size_t)grow*64 + lane];
        cs[wv][r][lane] = bf2f(v0[(size_t)grow*64 + lane]);
        degv[r] = (float)(off[grow + 1] - off[grow]);
    }
    {   // stage 1 -> u in xs
        float wa[64], wb[64];
#pragma unroll
        for (int k = 0; k < 64; ++k) { wa[k] = Fv[k*64 + lane]; wb[k] = OW0B[k*64 + lane]; }
        const float g_l = gv[lane], b_l = ob0[lane];
#pragma unroll
        for (int r = 0; r < 8; ++r) {
            float acc = fmaf(degv[r], g_l, b_l);
#pragma unroll
            for (int k4 = 0; k4 < 16; ++k4) {
                float4 x4 = *(const float4*)&xs[wv][r][k4*4];
                float4 c4 = *(const float4*)&cs[wv][r][k4*4];
                acc = fmaf(x4.x, wa[k4*4+0], acc); acc = fmaf(c4.x, wb[k4*4+0], acc);
                acc = fmaf(x4.y, wa[k4*4+1], acc); acc = fmaf(c4.y, wb[k4*4+1], acc);
                acc = fmaf(x4.z, wa[k4*4+2], acc); acc = fmaf(c4.z, wb[k4*4+2], acc);
                acc = fmaf(x4.w, wa[k4*4+3], acc); acc = fmaf(c4.w, wb[k4*4+3], acc);
            }
            xs[wv][r][lane] = fmaxf(acc, 0.f);
        }
    }
    {   // stage 2: both heads
        float wp[64], wq[64];
#pragma unroll
        for (int k = 0; k < 64; ++k) { wp[k] = Pw[k*64 + lane]; wq[k] = Vw[k*64 + lane]; }
        const float pb_l = pbp[lane], vb_l = vbp[lane];
        const float p1w = pw1[lane], v1w = vw1[lane];
        const float vbias = vb1[0];
#pragma unroll
        for (int r = 0; r < 8; ++r) {
            float tp = pb_l, tv = vb_l;
#pragma unroll
            for (int k4 = 0; k4 < 16; ++k4) {
                float4 u4 = *(const float4*)&xs[wv][r][k4*4];
                tp = fmaf(u4.x, wp[k4*4+0], tp); tv = fmaf(u4.x, wq[k4*4+0], tv);
                tp = fmaf(u4.y, wp[k4*4+1], tp); tv = fmaf(u4.y, wq[k4*4+1], tv);
                tp = fmaf(u4.z, wp[k4*4+2], tp); tv = fmaf(u4.z, wq[k4*4+2], tv);
                tp = fmaf(u4.w, wp[k4*4+3], tp); tv = fmaf(u4.w, wq[k4*4+3], tv);
            }
            tp = fmaxf(tp, 0.f) * p1w;
            tv = fmaxf(tv, 0.f) * v1w;
#pragma unroll
            for (int m = 32; m >= 1; m >>= 1) {
                tp += __shfl_xor(tp, m, 64);
                tv += __shfl_xor(tv, m, 64);
            }
            int row = rowTile + r;
            if (lane == 0 && row < M) {
                out[row]     = tv + vbias;  // value
                out[M + row] = tp;          // policy
            }
        }
    }
}

// =============== host launch ===============
#define AL256(x) (((x) + 255) & ~(size_t)255)

extern "C" void kernel_launch(void* const* d_in, const int* in_sizes, int n_in,
                              void* d_out, int out_size, void* d_ws, size_t ws_size,
                              hipStream_t stream)
{
    const float* cf  = (const float*)d_in[0];
    const int*   ei  = (const int*)  d_in[1];
    const float* ef  = (const float*)d_in[2];
    const float* vf  = (const float*)d_in[3];

    const float* cw0 = (const float*)d_in[4];
    const float* cb0 = (const float*)d_in[5];
    const float* cw1 = (const float*)d_in[6];
    const float* cb1 = (const float*)d_in[7];
    const float* vw0 = (const float*)d_in[8];
    const float* vb0 = (const float*)d_in[9];
    const float* vw1 = (const float*)d_in[10];
    const float* vb1 = (const float*)d_in[11];

    const float* vc_lw  = (const float*)d_in[12];
    const float* vc_lb  = (const float*)d_in[13];
    const float* vc_ew  = (const float*)d_in[14];
    const float* vc_rw  = (const float*)d_in[15];
    const float* vc_fw  = (const float*)d_in[16];
    const float* vc_fb  = (const float*)d_in[17];
    const float* vc_ow0 = (const float*)d_in[18];
    const float* vc_ob0 = (const float*)d_in[19];
    const float* vc_ow1 = (const float*)d_in[20];
    const float* vc_ob1 = (const float*)d_in[21];

    const float* cv_lw  = (const float*)d_in[22];
    const float* cv_lb  = (const float*)d_in[23];
    const float* cv_ew  = (const float*)d_in[24];
    const float* cv_rw  = (const float*)d_in[25];
    const float* cv_fw  = (const float*)d_in[26];
    const float* cv_fb  = (const float*)d_in[27];
    const float* cv_ow0 = (const float*)d_in[28];
    const float* cv_ob0 = (const float*)d_in[29];
    const float* cv_ow1 = (const float*)d_in[30];
    const float* cv_ob1 = (const float*)d_in[31];

    const float* pw0  = (const float*)d_in[32];
    const float* pb0  = (const float*)d_in[33];
    const float* pw1  = (const float*)d_in[34];
    const float* vhw0 = (const float*)d_in[35];
    const float* vhb0 = (const float*)d_in[36];
    const float* vhw1 = (const float*)d_in[37];
    const float* vhb1 = (const float*)d_in[38];

    const int NC = in_sizes[0] / 5;
    const int E  = in_sizes[1] / 2;
    const int NV = in_sizes[3] / 19;
    const int* eic = ei;
    const int* eiv = ei + E;

    // ---- workspace layout ----
    char* base = (char*)d_ws;
    size_t o = 0;
    float*  RlC = (float*)(base + o);  o += AL256((size_t)NC*64*4);
    u16*    c0b = (u16*)  (base + o);  o += AL256((size_t)NC*64*2);
    u16*    LsC = (u16*)  (base + o);  o += AL256((size_t)NC*64*2);
    float*  RlV = (float*)(base + o);  o += AL256((size_t)NV*64*4);
    u16*    v0b = (u16*)  (base + o);  o += AL256((size_t)NV*64*2);
    u16*    LsV = (u16*)  (base + o);  o += AL256((size_t)NV*64*2);
    float2* bktC = (float2*)(base + o); o += AL256((size_t)E*8);
    float2* bktV = (float2*)(base + o); o += AL256((size_t)E*8);
    int* cntC = (int*)(base + o);  o += AL256((size_t)NC*4);
    int* offC = (int*)(base + o);  o += AL256(((size_t)NC + 1)*4);
    int* cntV = (int*)(base + o);  o += AL256((size_t)NV*4);
    int* offV = (int*)(base + o);  o += AL256(((size_t)NV + 1)*4);
    int* blks = (int*)(base + o);  o += AL256((size_t)1024*4);
    int* blkex= (int*)(base + o);  o += AL256((size_t)1024*4);
    float* Fc  = (float*)(base + o); o += AL256((size_t)4096*4);
    float* Hc  = (float*)(base + o); o += AL256((size_t)4096*4);
    float* Fv  = (float*)(base + o); o += AL256((size_t)4096*4);
    float* Pw  = (float*)(base + o); o += AL256((size_t)4096*4);
    float* Vw  = (float*)(base + o); o += AL256((size_t)4096*4);
    float* gc  = (float*)(base + o); o += AL256((size_t)64*4);
    float* hc  = (float*)(base + o); o += AL256((size_t)64*4);
    float* gv  = (float*)(base + o); o += AL256((size_t)64*4);
    float* pbp = (float*)(base + o); o += AL256((size_t)64*4);
    float* vbp = (float*)(base + o); o += AL256((size_t)64*4);

    if (o > ws_size) return;  // insufficient scratch: fail visibly

    dim3 blk(256);
    dim3 gRowsC((unsigned)((NC + 31) / 32));
    dim3 gRowsV((unsigned)((NV + 31) / 32));
    dim3 gNodeC((unsigned)((NC + 3) / 4));
    dim3 gNodeV((unsigned)((NV + 3) / 4));
    dim3 gE((unsigned)((E + 255) / 256));
    const int nbC = (NC + 1023) / 1024;
    const int nbV = (NV + 1023) / 1024;

    // ---- counting sort setup ----
    (void)hipMemsetAsync(cntC, 0, (size_t)NC*4, stream);
    (void)hipMemsetAsync(cntV, 0, (size_t)NV*4, stream);
    hist2_kernel<<<gE, blk, 0, stream>>>(eic, eiv, cntC, cntV, E);
    scan1_kernel<<<dim3(nbC), blk, 0, stream>>>(cntC, blks, NC);
    scan2_kernel<<<dim3(1),   blk, 0, stream>>>(blks, blkex, nbC);
    scan3_kernel<<<dim3(nbC), blk, 0, stream>>>(cntC, blkex, offC, NC);
    scan1_kernel<<<dim3(nbV), blk, 0, stream>>>(cntV, blks, NV);
    scan2_kernel<<<dim3(1),   blk, 0, stream>>>(blks, blkex, nbV);
    scan3_kernel<<<dim3(nbV), blk, 0, stream>>>(cntV, blkex, offV, NV);

    // ---- collapsed weights ----
    prep_kernel<<<dim3(1), blk, 0, stream>>>(
        vc_fw, vc_fb, vc_ow0, vc_ow1, vc_ob1,
        cv_rw, cv_fw, cv_fb, cv_ow0, cv_ow1, cv_ob1,
        pw0, pb0, vhw0, vhb0,
        Fc, gc, Hc, hc, Fv, gv, Pw, pbp, Vw, vbp);

    // ---- embeddings (+ fused per-node linears) ----
    embc_kernel<<<gRowsC, blk, 0, stream>>>(cf, cw0, cb0, cw1, cb1,
                                            vc_lw, vc_lb, c0b, RlC, NC);
    embv_kernel<<<gRowsV, blk, 0, stream>>>(vf, vw0, vb0, vw1, vb1,
                                            vc_rw, cv_lw, cv_lb, v0b, LsV, RlV, NV);

    // ---- single-pass scatter into both dst-sorted buckets ----
    (void)hipMemcpyAsync(cntC, offC, (size_t)NC*4, hipMemcpyDeviceToDevice, stream);
    (void)hipMemcpyAsync(cntV, offV, (size_t)NV*4, hipMemcpyDeviceToDevice, stream);
    scatter2_kernel<<<gE, blk, 0, stream>>>(eic, eiv, ef, cntC, cntV, bktC, bktV, E);

    // ---- conv1: v -> c ----
    agg_kernel<<<gNodeC, blk, 0, stream>>>(offC, bktC, RlC, LsV, vc_ew, NC);
    consupd_kernel<<<gRowsC, blk, 0, stream>>>(RlC, c0b, offC,
                                               Fc, vc_ow0 + 64*64, gc, vc_ob0,
                                               Hc, hc, LsC, NC);

    // ---- conv2: c -> v ----
    agg_kernel<<<gNodeV, blk, 0, stream>>>(offV, bktV, RlV, LsC, cv_ew, NV);
    varupdhead_kernel<<<gRowsV, blk, 0, stream>>>(RlV, v0b, offV,
                                                  Fv, cv_ow0 + 64*64, gv, cv_ob0,
                                                  Pw, pbp, pw1, Vw, vbp, vhw1, vhb1,
                                                  (float*)d_out, NV);
}